// Round 3
// baseline (41218.500 us; speedup 1.0000x reference)
//
#include <hip/hip_runtime.h>

#define NN 50000
#define FF 24
#define HH 128
#define TT 12
#define EE 800000
#define HORZ 6

// ---------------- mask dtype detection + canonicalization ----------------

__global__ void k_maskdetect(const unsigned char* __restrict__ m, int* __restrict__ flag) {
    int i = blockIdx.x * 256 + threadIdx.x;
    if (i < 16384 && (i & 3) != 0 && m[i] != 0) atomicOr(flag, 1);
}

__global__ void k_maskconv(const unsigned char* __restrict__ mraw, const int* __restrict__ flag,
                           unsigned char* __restrict__ mout) {
    int i = blockIdx.x * 256 + threadIdx.x;
    if (i >= TT * NN) return;
    if (*flag) mout[i] = (mraw[i] != 0);
    else       mout[i] = (((const int*)mraw)[i] != 0);
}

// ---------------- CSR build: histogram -> scan -> fill ----------------

__global__ void k_hist(const int* __restrict__ ei, int* __restrict__ cnt) {
    int idx = blockIdx.x * 256 + threadIdx.x;          // over T*E
    if (idx >= TT * EE) return;
    int t = idx / EE, e = idx - t * EE;
    int dst = ei[((size_t)t * 2 + 1) * EE + e];
    atomicAdd(&cnt[t * NN + dst], 1);
}

__global__ void k_scan(const int* __restrict__ cnt, int* __restrict__ offs) {
    __shared__ int sums[1024];
    int t = blockIdx.x, tid = threadIdx.x;
    const int per = (NN + 1023) / 1024;                // 49
    int base = tid * per;
    int s = 0;
    for (int i = 0; i < per; i++) {
        int idx = base + i;
        if (idx < NN) s += cnt[t * NN + idx];
    }
    sums[tid] = s;
    __syncthreads();
    for (int off = 1; off < 1024; off <<= 1) {
        int tv = (tid >= off) ? sums[tid - off] : 0;
        __syncthreads();
        sums[tid] += tv;
        __syncthreads();
    }
    int run = sums[tid] - s;                           // exclusive prefix
    for (int i = 0; i < per; i++) {
        int idx = base + i;
        if (idx < NN) { offs[t * (NN + 1) + idx] = run; run += cnt[t * NN + idx]; }
    }
    if (tid == 1023) offs[t * (NN + 1) + NN] = sums[1023];
}

__global__ void k_prep(const int* __restrict__ offs, int* __restrict__ cursor) {
    int idx = blockIdx.x * 256 + threadIdx.x;          // over T*N
    if (idx >= TT * NN) return;
    int t = idx / NN, n = idx - t * NN;
    cursor[idx] = offs[t * (NN + 1) + n];
}

__global__ void k_fill(const int* __restrict__ ei, const float* __restrict__ ea,
                       int* __restrict__ cursor, int* __restrict__ srcs,
                       float* __restrict__ eav) {
    int idx = blockIdx.x * 256 + threadIdx.x;          // over T*E
    if (idx >= TT * EE) return;
    int t = idx / EE, e = idx - t * EE;
    int dst = ei[((size_t)t * 2 + 1) * EE + e];
    int src = ei[((size_t)t * 2 + 0) * EE + e];
    int pos = atomicAdd(&cursor[t * NN + dst], 1);
    srcs[(size_t)t * EE + pos] = src;
    eav[(size_t)t * EE + pos]  = ea[(size_t)t * EE + e];
}

// deg[n] = sum of incoming ea; dinv = rsqrt(deg+1)
__global__ void k_degdinv(const int* __restrict__ offs, const float* __restrict__ eav,
                          float* __restrict__ dinv) {
    int idx = blockIdx.x * 256 + threadIdx.x;          // over T*N
    if (idx >= TT * NN) return;
    int t = idx / NN, n = idx - t * NN;
    int b = offs[t * (NN + 1) + n], en = offs[t * (NN + 1) + n + 1];
    float s = 0.f;
    for (int j = b; j < en; j++) s += eav[(size_t)t * EE + j];
    dinv[idx] = rsqrtf(s + 1.0f);
}

// eav[slot] *= dinv[src]*dinv[dst]  (becomes the full edge coefficient)
__global__ void k_coef(const int* __restrict__ offs, const int* __restrict__ srcs,
                       const float* __restrict__ dinv, float* __restrict__ eav) {
    int idx = blockIdx.x * 256 + threadIdx.x;          // over T*N
    if (idx >= TT * NN) return;
    int t = idx / NN, n = idx - t * NN;
    int b = offs[t * (NN + 1) + n], en = offs[t * (NN + 1) + n + 1];
    float di = dinv[idx];
    for (int j = b; j < en; j++) {
        int s = srcs[(size_t)t * EE + j];
        eav[(size_t)t * EE + j] *= di * dinv[t * NN + s];
    }
}

// ---------------- weight folding: Cg = Wg @ LWg[0:128], b2g = bg @ LWg[0:128] + Lbg ----------------

__global__ void k_fold(const float* __restrict__ Wz, const float* __restrict__ Wr,
                       const float* __restrict__ Wh,
                       const float* __restrict__ bz, const float* __restrict__ br,
                       const float* __restrict__ bh,
                       const float* __restrict__ LWz, const float* __restrict__ LWr,
                       const float* __restrict__ LWh,
                       const float* __restrict__ Lbz, const float* __restrict__ Lbr,
                       const float* __restrict__ Lbh,
                       float* __restrict__ Call, float* __restrict__ b2) {
    int g = blockIdx.x, c = threadIdx.x;               // 3 blocks x 128
    const float* W  = g == 0 ? Wz : (g == 1 ? Wr : Wh);
    const float* LW = g == 0 ? LWz : (g == 1 ? LWr : LWh);
    const float* bg = g == 0 ? bz : (g == 1 ? br : bh);
    const float* Lb = g == 0 ? Lbz : (g == 1 ? Lbr : Lbh);
    for (int j = 0; j < FF; j++) {
        float a = 0.f;
        for (int k = 0; k < HH; k++) a += W[j * HH + k] * LW[k * HH + c];
        Call[((size_t)g * FF + j) * HH + c] = a;
    }
    float a = Lb[c];
    for (int k = 0; k < HH; k++) a += bg[k] * LW[k * HH + c];
    b2[g * HH + c] = a;
}

// ---------------- gather: xe[n][f] = x[n][f]*dinv^2 + sum_e coef*x[src][f] ----------------

__global__ void k_gather(const float* __restrict__ x, const int* __restrict__ offs,
                         const int* __restrict__ srcs, const float* __restrict__ eav,
                         const float* __restrict__ dinv, float* __restrict__ xe) {
    int idx = blockIdx.x * 256 + threadIdx.x;          // over N*F
    if (idx >= NN * FF) return;
    int n = idx / FF, f = idx - n * FF;
    int b = offs[n], en = offs[n + 1];
    float di = dinv[n];
    float acc = x[idx] * di * di;
    for (int j = b; j < en; j++) {
        acc += x[srcs[j] * FF + f] * eav[j];
    }
    xe[idx] = acc;
}

// ---------------- fused GRU cell (weight-stationary, LDS-broadcast activations) ----------------

#define ACC_ROW(acc, srow, wreg, LEN) \
    _Pragma("unroll") \
    for (int q = 0; q < (LEN); q += 4) { \
        float4 v_ = *(const float4*)&(srow)[q]; \
        acc += v_.x * wreg[q] + v_.y * wreg[q + 1] + v_.z * wreg[q + 2] + v_.w * wreg[q + 3]; \
    }

template <int DOHEAD>
__global__ __launch_bounds__(256, 2) void k_cell(
        const float* __restrict__ xe, const float* __restrict__ hin,
        const unsigned char* __restrict__ gmask,
        const float* __restrict__ Call, const float* __restrict__ b2,
        const float* __restrict__ LWz, const float* __restrict__ LWr,
        const float* __restrict__ LWh,
        const unsigned char* __restrict__ wmask, float* __restrict__ hout,
        const float* __restrict__ headW, const float* __restrict__ headb,
        float* __restrict__ y) {
    __shared__ float s_xe[16][FF];
    __shared__ float s_h0[16][HH];
    __shared__ float s_z[16][HH];
    __shared__ float s_hr[16][HH];
    int nb = blockIdx.x * 16;
    int tid = threadIdx.x;

    for (int i = tid; i < 16 * FF; i += 256) {
        s_xe[i / FF][i % FF] = xe[(size_t)nb * FF + i];
    }
    for (int i = tid; i < 16 * HH; i += 256) {
        int m = i >> 7, k = i & 127;
        float v = hin[((size_t)nb + m) * HH + k];
        if (gmask && !gmask[nb + m]) v = 0.f;
        s_h0[m][k] = v;
    }
    __syncthreads();

    // ---- phase A: z (cols 0..127 by threads g=0) and r->h*r (g=1) ----
    {
        int g = tid >> 7, cc = tid & 127;
        const float* Cg  = g ? (Call + FF * HH) : Call;
        const float* LWg = g ? LWr : LWz;
        float wx[FF];
#pragma unroll
        for (int j = 0; j < FF; j++) wx[j] = Cg[j * HH + cc];
        float wh[HH];
#pragma unroll
        for (int k = 0; k < HH; k++) wh[k] = LWg[(HH + k) * HH + cc];
        float bb = b2[g * HH + cc];
        for (int ch = 0; ch < 4; ch++) {
            int m0 = ch * 4;
            float a0 = bb, a1 = bb, a2 = bb, a3 = bb;
            ACC_ROW(a0, s_xe[m0 + 0], wx, FF); ACC_ROW(a1, s_xe[m0 + 1], wx, FF);
            ACC_ROW(a2, s_xe[m0 + 2], wx, FF); ACC_ROW(a3, s_xe[m0 + 3], wx, FF);
            ACC_ROW(a0, s_h0[m0 + 0], wh, HH); ACC_ROW(a1, s_h0[m0 + 1], wh, HH);
            ACC_ROW(a2, s_h0[m0 + 2], wh, HH); ACC_ROW(a3, s_h0[m0 + 3], wh, HH);
            float s0 = 1.f / (1.f + __expf(-a0));
            float s1 = 1.f / (1.f + __expf(-a1));
            float s2 = 1.f / (1.f + __expf(-a2));
            float s3 = 1.f / (1.f + __expf(-a3));
            if (g == 0) {
                s_z[m0 + 0][cc] = s0; s_z[m0 + 1][cc] = s1;
                s_z[m0 + 2][cc] = s2; s_z[m0 + 3][cc] = s3;
            } else {
                s_hr[m0 + 0][cc] = s0 * s_h0[m0 + 0][cc];
                s_hr[m0 + 1][cc] = s1 * s_h0[m0 + 1][cc];
                s_hr[m0 + 2][cc] = s2 * s_h0[m0 + 2][cc];
                s_hr[m0 + 3][cc] = s3 * s_h0[m0 + 3][cc];
            }
        }
    }
    __syncthreads();

    // ---- phase B: htil + GRU update (rows split: tid<128 rows 0-7, else 8-15) ----
    {
        int rh = tid >> 7, c = tid & 127;
        const float* Ch = Call + 2 * FF * HH;
        float wx2[FF];
#pragma unroll
        for (int j = 0; j < FF; j++) wx2[j] = Ch[j * HH + c];
        float wh2[HH];
#pragma unroll
        for (int k = 0; k < HH; k++) wh2[k] = LWh[(HH + k) * HH + c];
        float bb2 = b2[2 * HH + c];
        for (int ch = 0; ch < 2; ch++) {
            int m0 = rh * 8 + ch * 4;
            float a0 = bb2, a1 = bb2, a2 = bb2, a3 = bb2;
            ACC_ROW(a0, s_xe[m0 + 0], wx2, FF); ACC_ROW(a1, s_xe[m0 + 1], wx2, FF);
            ACC_ROW(a2, s_xe[m0 + 2], wx2, FF); ACC_ROW(a3, s_xe[m0 + 3], wx2, FF);
            ACC_ROW(a0, s_hr[m0 + 0], wh2, HH); ACC_ROW(a1, s_hr[m0 + 1], wh2, HH);
            ACC_ROW(a2, s_hr[m0 + 2], wh2, HH); ACC_ROW(a3, s_hr[m0 + 3], wh2, HH);
#pragma unroll
            for (int i = 0; i < 4; i++) {
                float a = (i == 0) ? a0 : (i == 1) ? a1 : (i == 2) ? a2 : a3;
                int m = m0 + i;
                float e2 = __expf(2.f * a);
                float ht = 1.f - 2.f / (e2 + 1.f);
                float z = s_z[m][c];
                float h0v = s_h0[m][c];
                float hn = z * h0v + (1.f - z) * ht;
                int n = nb + m;
                if (wmask) {
                    if (wmask[n]) hout[(size_t)n * HH + c] = hn;
                } else {
                    hout[(size_t)n * HH + c] = hn;
                }
                if (DOHEAD) s_z[m][c] = hn;
            }
        }
    }

    if (DOHEAD) {
        __syncthreads();
        for (int i = tid; i < 16 * FF; i += 256) {
            int m = i / FF, f = i - m * FF;
            float acc = headb[f];
#pragma unroll 8
            for (int cJ = 0; cJ < HH; cJ++) acc += s_z[m][cJ] * headW[cJ * FF + f];
            y[(size_t)nb * FF + i] = acc;
        }
    }
}

extern "C" void kernel_launch(void* const* d_in, const int* in_sizes, int n_in,
                              void* d_out, int out_size, void* d_ws, size_t ws_size,
                              hipStream_t stream) {
    const float* x_seq = (const float*)d_in[0];
    const int*   ei    = (const int*)d_in[1];
    const float* ea    = (const float*)d_in[2];
    const unsigned char* mraw = (const unsigned char*)d_in[3];
    const float* Wz  = (const float*)d_in[5];
    const float* Wr  = (const float*)d_in[6];
    const float* Wh  = (const float*)d_in[7];
    const float* bz  = (const float*)d_in[8];
    const float* br  = (const float*)d_in[9];
    const float* bh  = (const float*)d_in[10];
    const float* LWz = (const float*)d_in[11];
    const float* LWr = (const float*)d_in[12];
    const float* LWh = (const float*)d_in[13];
    const float* Lbz = (const float*)d_in[14];
    const float* Lbr = (const float*)d_in[15];
    const float* Lbh = (const float*)d_in[16];
    const float* headW = (const float*)d_in[17];
    const float* headb = (const float*)d_in[18];
    float* out = (float*)d_out;

    char* wp = (char*)d_ws;
    int*   cnt    = (int*)wp;   wp += sizeof(int) * TT * NN;          // histogram, then cursor
    int*   offs   = (int*)wp;   wp += sizeof(int) * TT * (NN + 1);
    int*   srcs   = (int*)wp;   wp += sizeof(int) * (size_t)TT * EE;
    float* eav    = (float*)wp; wp += sizeof(float) * (size_t)TT * EE;
    float* dinv   = (float*)wp; wp += sizeof(float) * TT * NN;
    float* hstore = (float*)wp; wp += sizeof(float) * (size_t)NN * HH;
    float* hp     = (float*)wp; wp += sizeof(float) * (size_t)NN * HH;
    float* xebuf  = (float*)wp; wp += sizeof(float) * NN * FF;
    float* Call   = (float*)wp; wp += sizeof(float) * 3 * FF * HH;
    float* b2     = (float*)wp; wp += sizeof(float) * 3 * HH;
    int*   mflag  = (int*)wp;   wp += 256;
    unsigned char* mask = (unsigned char*)wp; wp += TT * NN;
    if (ws_size < (size_t)(wp - (char*)d_ws)) return;

    hipMemsetAsync(mflag, 0, sizeof(int), stream);
    k_maskdetect<<<64, 256, 0, stream>>>(mraw, mflag);
    k_maskconv<<<(TT * NN + 255) / 256, 256, 0, stream>>>(mraw, mflag, mask);

    // CSR build + norm coefficients (once for all 12 graphs)
    hipMemsetAsync(cnt, 0, sizeof(int) * TT * NN, stream);
    hipMemsetAsync(hstore, 0, sizeof(float) * NN * HH, stream);
    k_hist<<<(TT * EE + 255) / 256, 256, 0, stream>>>(ei, cnt);
    k_scan<<<TT, 1024, 0, stream>>>(cnt, offs);
    k_prep<<<(TT * NN + 255) / 256, 256, 0, stream>>>(offs, cnt);
    k_fill<<<(TT * EE + 255) / 256, 256, 0, stream>>>(ei, ea, cnt, srcs, eav);
    k_degdinv<<<(TT * NN + 255) / 256, 256, 0, stream>>>(offs, eav, dinv);
    k_coef<<<(TT * NN + 255) / 256, 256, 0, stream>>>(offs, srcs, dinv, eav);
    k_fold<<<3, 128, 0, stream>>>(Wz, Wr, Wh, bz, br, bh, LWz, LWr, LWh, Lbz, Lbr, Lbh, Call, b2);

    // ---------------- encoder ----------------
    for (int t = 0; t < TT; t++) {
        const float* xt = x_seq + (size_t)t * NN * FF;
        const unsigned char* mt = mask + (size_t)t * NN;
        k_gather<<<(NN * FF + 255) / 256, 256, 0, stream>>>(
            xt, offs + t * (NN + 1), srcs + (size_t)t * EE, eav + (size_t)t * EE,
            dinv + t * NN, xebuf);
        k_cell<0><<<NN / 16, 256, 0, stream>>>(
            xebuf, hstore, mt, Call, b2, LWz, LWr, LWh, mt, hstore,
            nullptr, nullptr, nullptr);
    }

    // ---------------- decoder ----------------
    const int*   offsl = offs + (TT - 1) * (NN + 1);
    const int*   srcsl = srcs + (size_t)(TT - 1) * EE;
    const float* eavl  = eav + (size_t)(TT - 1) * EE;
    const float* dil   = dinv + (TT - 1) * NN;
    for (int k = 0; k < HORZ; k++) {
        const float* xin = (k == 0) ? (x_seq + (size_t)(TT - 1) * NN * FF)
                                    : (out + (size_t)(k - 1) * NN * FF);
        k_gather<<<(NN * FF + 255) / 256, 256, 0, stream>>>(
            xin, offsl, srcsl, eavl, dil, xebuf);
        k_cell<1><<<NN / 16, 256, 0, stream>>>(
            xebuf, (k == 0) ? hstore : hp,
            (k == 0) ? (mask + (size_t)(TT - 1) * NN) : nullptr,
            Call, b2, LWz, LWr, LWh, nullptr, hp,
            headW, headb, out + (size_t)k * NN * FF);
    }
}

// Round 4
// 5120.767 us; speedup vs baseline: 8.0493x; 8.0493x over previous
//
#include <hip/hip_runtime.h>

#define NN 50000
#define FF 24
#define HH 128
#define TT 12
#define EE 800000
#define HORZ 6

// ---------------- mask dtype detection + canonicalization ----------------

__global__ void k_maskdetect(const unsigned char* __restrict__ m, int* __restrict__ flag) {
    int i = blockIdx.x * 256 + threadIdx.x;
    if (i < 16384 && (i & 3) != 0 && m[i] != 0) atomicOr(flag, 1);
}

__global__ void k_maskconv(const unsigned char* __restrict__ mraw, const int* __restrict__ flag,
                           unsigned char* __restrict__ mout) {
    int i = blockIdx.x * 256 + threadIdx.x;
    if (i >= TT * NN) return;
    if (*flag) mout[i] = (mraw[i] != 0);
    else       mout[i] = (((const int*)mraw)[i] != 0);
}

// ---------------- CSR build: histogram -> scan(+cursor) -> fill ----------------

__global__ void k_hist(const int* __restrict__ ei, int* __restrict__ cnt) {
    int idx = blockIdx.x * 256 + threadIdx.x;          // over T*E
    if (idx >= TT * EE) return;
    int t = idx / EE, e = idx - t * EE;
    int dst = ei[((size_t)t * 2 + 1) * EE + e];
    atomicAdd(&cnt[t * NN + dst], 1);
}

__global__ void k_scan(const int* __restrict__ cnt, int* __restrict__ offs,
                       int* __restrict__ cursor) {
    __shared__ int sums[1024];
    int t = blockIdx.x, tid = threadIdx.x;
    const int per = (NN + 1023) / 1024;                // 49
    int base = tid * per;
    int s = 0;
    for (int i = 0; i < per; i++) {
        int idx = base + i;
        if (idx < NN) s += cnt[t * NN + idx];
    }
    sums[tid] = s;
    __syncthreads();
    for (int off = 1; off < 1024; off <<= 1) {
        int tv = (tid >= off) ? sums[tid - off] : 0;
        __syncthreads();
        sums[tid] += tv;
        __syncthreads();
    }
    int run = sums[tid] - s;                           // exclusive prefix
    for (int i = 0; i < per; i++) {
        int idx = base + i;
        if (idx < NN) {
            offs[t * (NN + 1) + idx] = run;
            cursor[t * NN + idx] = run;
            run += cnt[t * NN + idx];
        }
    }
    if (tid == 1023) offs[t * (NN + 1) + NN] = sums[1023];
}

__global__ void k_fill(const int* __restrict__ ei, const float* __restrict__ ea,
                       int* __restrict__ cursor, int* __restrict__ srcs,
                       float* __restrict__ eav) {
    int idx = blockIdx.x * 256 + threadIdx.x;          // over T*E
    if (idx >= TT * EE) return;
    int t = idx / EE, e = idx - t * EE;
    int dst = ei[((size_t)t * 2 + 1) * EE + e];
    int src = ei[((size_t)t * 2 + 0) * EE + e];
    int pos = atomicAdd(&cursor[t * NN + dst], 1);
    srcs[(size_t)t * EE + pos] = src;
    eav[(size_t)t * EE + pos]  = ea[(size_t)t * EE + e];
}

// deg[n] = sum of incoming ea; dinv = rsqrt(deg+1)
__global__ void k_degdinv(const int* __restrict__ offs, const float* __restrict__ eav,
                          float* __restrict__ dinv) {
    int idx = blockIdx.x * 256 + threadIdx.x;          // over T*N
    if (idx >= TT * NN) return;
    int t = idx / NN, n = idx - t * NN;
    int b = offs[t * (NN + 1) + n], en = offs[t * (NN + 1) + n + 1];
    float s = 0.f;
    for (int j = b; j < en; j++) s += eav[(size_t)t * EE + j];
    dinv[idx] = rsqrtf(s + 1.0f);
}

// eav[slot] *= dinv[src]*dinv[dst]  (full edge coefficient)
__global__ void k_coef(const int* __restrict__ offs, const int* __restrict__ srcs,
                       const float* __restrict__ dinv, float* __restrict__ eav) {
    int idx = blockIdx.x * 256 + threadIdx.x;          // over T*N
    if (idx >= TT * NN) return;
    int t = idx / NN, n = idx - t * NN;
    int b = offs[t * (NN + 1) + n], en = offs[t * (NN + 1) + n + 1];
    float di = dinv[idx];
    for (int j = b; j < en; j++) {
        int s = srcs[(size_t)t * EE + j];
        eav[(size_t)t * EE + j] *= di * dinv[t * NN + s];
    }
}

// ---------------- weight folding: Cg = Wg @ LWg[0:H], b2g = bg @ LWg[0:H] + Lbg ----------------

__global__ void k_fold(const float* __restrict__ Wz, const float* __restrict__ Wr,
                       const float* __restrict__ Wh,
                       const float* __restrict__ bz, const float* __restrict__ br,
                       const float* __restrict__ bh,
                       const float* __restrict__ LWz, const float* __restrict__ LWr,
                       const float* __restrict__ LWh,
                       const float* __restrict__ Lbz, const float* __restrict__ Lbr,
                       const float* __restrict__ Lbh,
                       float* __restrict__ Call, float* __restrict__ b2) {
    int g = blockIdx.x, c = threadIdx.x;               // 3 blocks x 128
    const float* W  = g == 0 ? Wz : (g == 1 ? Wr : Wh);
    const float* LW = g == 0 ? LWz : (g == 1 ? LWr : LWh);
    const float* bg = g == 0 ? bz : (g == 1 ? br : bh);
    const float* Lb = g == 0 ? Lbz : (g == 1 ? Lbr : Lbh);
    for (int j = 0; j < FF; j++) {
        float a = 0.f;
        for (int k = 0; k < HH; k++) a += W[j * HH + k] * LW[k * HH + c];
        Call[((size_t)g * FF + j) * HH + c] = a;
    }
    float a = Lb[c];
    for (int k = 0; k < HH; k++) a += bg[k] * LW[k * HH + c];
    b2[g * HH + c] = a;
}

// ---------------- gather: xe[n][f] = x[n][f]*dinv^2 + sum_e coef*x[src][f] ----------------

__global__ void k_gather(const float* __restrict__ x, const int* __restrict__ offs,
                         const int* __restrict__ srcs, const float* __restrict__ eav,
                         const float* __restrict__ dinv, float* __restrict__ xe) {
    int idx = blockIdx.x * 256 + threadIdx.x;          // over N*F
    if (idx >= NN * FF) return;
    int n = idx / FF, f = idx - n * FF;
    int b = offs[n], en = offs[n + 1];
    float di = dinv[n];
    float acc = x[idx] * di * di;
    for (int j = b; j < en; j++) {
        acc += x[srcs[j] * FF + f] * eav[j];
    }
    xe[idx] = acc;
}

// ---------------- fused GRU cell: no spills, weights streamed via L1/L2 ----------------
// 8 named accumulators per chunk; 4 weight scalars per k-group; activations float4 from LDS.

#define FMA8X(SARR, M0, K)                                                        \
    {                                                                             \
        float4 v_;                                                                \
        v_ = *(const float4*)&SARR[M0 + 0][K]; a0 += v_.x*w0 + v_.y*w1 + v_.z*w2 + v_.w*w3; \
        v_ = *(const float4*)&SARR[M0 + 1][K]; a1 += v_.x*w0 + v_.y*w1 + v_.z*w2 + v_.w*w3; \
        v_ = *(const float4*)&SARR[M0 + 2][K]; a2 += v_.x*w0 + v_.y*w1 + v_.z*w2 + v_.w*w3; \
        v_ = *(const float4*)&SARR[M0 + 3][K]; a3 += v_.x*w0 + v_.y*w1 + v_.z*w2 + v_.w*w3; \
        v_ = *(const float4*)&SARR[M0 + 4][K]; a4 += v_.x*w0 + v_.y*w1 + v_.z*w2 + v_.w*w3; \
        v_ = *(const float4*)&SARR[M0 + 5][K]; a5 += v_.x*w0 + v_.y*w1 + v_.z*w2 + v_.w*w3; \
        v_ = *(const float4*)&SARR[M0 + 6][K]; a6 += v_.x*w0 + v_.y*w1 + v_.z*w2 + v_.w*w3; \
        v_ = *(const float4*)&SARR[M0 + 7][K]; a7 += v_.x*w0 + v_.y*w1 + v_.z*w2 + v_.w*w3; \
    }

template <int DOHEAD>
__global__ __launch_bounds__(256) void k_cell(
        const float* __restrict__ xe, const float* __restrict__ hin,
        const unsigned char* __restrict__ gmask,
        const float* __restrict__ Call, const float* __restrict__ b2,
        const float* __restrict__ LWz, const float* __restrict__ LWr,
        const float* __restrict__ LWh,
        const unsigned char* __restrict__ wmask, float* __restrict__ hout,
        const float* __restrict__ headW, const float* __restrict__ headb,
        float* __restrict__ y) {
    __shared__ float s_xe[16][FF];
    __shared__ float s_h0[16][HH];
    __shared__ float s_z[16][HH];
    __shared__ float s_hr[16][HH];
    int nb = blockIdx.x * 16;
    int tid = threadIdx.x;

    for (int i = tid; i < 16 * FF; i += 256) {
        s_xe[i / FF][i % FF] = xe[(size_t)nb * FF + i];
    }
    for (int i = tid; i < 16 * HH; i += 256) {
        int m = i >> 7, k = i & 127;
        float v = hin[((size_t)nb + m) * HH + k];
        if (gmask && !gmask[nb + m]) v = 0.f;
        s_h0[m][k] = v;
    }
    __syncthreads();

    int g = tid >> 7, c = tid & 127;

    // ---- phase A: z (g=0) and r -> h*r (g=1), 2 chunks of 8 rows ----
    {
        const float* Cg   = Call + (size_t)g * FF * HH;
        const float* LWgb = (g ? LWr : LWz) + (size_t)HH * HH;   // bottom half
        float bb = b2[g * HH + c];
#pragma unroll
        for (int ch = 0; ch < 2; ch++) {
            int m0 = ch * 8;
            float a0 = bb, a1 = bb, a2 = bb, a3 = bb, a4 = bb, a5 = bb, a6 = bb, a7 = bb;
#pragma unroll
            for (int k = 0; k < FF; k += 4) {
                float w0 = Cg[(k + 0) * HH + c], w1 = Cg[(k + 1) * HH + c];
                float w2 = Cg[(k + 2) * HH + c], w3 = Cg[(k + 3) * HH + c];
                FMA8X(s_xe, m0, k);
            }
#pragma unroll 4
            for (int k = 0; k < HH; k += 4) {
                float w0 = LWgb[(k + 0) * HH + c], w1 = LWgb[(k + 1) * HH + c];
                float w2 = LWgb[(k + 2) * HH + c], w3 = LWgb[(k + 3) * HH + c];
                FMA8X(s_h0, m0, k);
            }
#pragma unroll
            for (int r = 0; r < 8; r++) {
                float a = (r == 0) ? a0 : (r == 1) ? a1 : (r == 2) ? a2 : (r == 3) ? a3
                        : (r == 4) ? a4 : (r == 5) ? a5 : (r == 6) ? a6 : a7;
                float s = 1.f / (1.f + __expf(-a));
                if (g == 0) s_z[m0 + r][c] = s;
                else        s_hr[m0 + r][c] = s * s_h0[m0 + r][c];
            }
        }
    }
    __syncthreads();

    // ---- phase B: htil + GRU update; g=0 rows 0-7, g=1 rows 8-15 ----
    {
        const float* Ch   = Call + (size_t)2 * FF * HH;
        const float* LWhb = LWh + (size_t)HH * HH;
        float bb = b2[2 * HH + c];
        int m0 = g * 8;
        float a0 = bb, a1 = bb, a2 = bb, a3 = bb, a4 = bb, a5 = bb, a6 = bb, a7 = bb;
#pragma unroll
        for (int k = 0; k < FF; k += 4) {
            float w0 = Ch[(k + 0) * HH + c], w1 = Ch[(k + 1) * HH + c];
            float w2 = Ch[(k + 2) * HH + c], w3 = Ch[(k + 3) * HH + c];
            FMA8X(s_xe, m0, k);
        }
#pragma unroll 4
        for (int k = 0; k < HH; k += 4) {
            float w0 = LWhb[(k + 0) * HH + c], w1 = LWhb[(k + 1) * HH + c];
            float w2 = LWhb[(k + 2) * HH + c], w3 = LWhb[(k + 3) * HH + c];
            FMA8X(s_hr, m0, k);
        }
#pragma unroll
        for (int r = 0; r < 8; r++) {
            float a = (r == 0) ? a0 : (r == 1) ? a1 : (r == 2) ? a2 : (r == 3) ? a3
                    : (r == 4) ? a4 : (r == 5) ? a5 : (r == 6) ? a6 : a7;
            int m = m0 + r;
            float e2 = __expf(2.f * a);
            float ht = 1.f - 2.f / (e2 + 1.f);
            float z = s_z[m][c];
            float h0v = s_h0[m][c];
            float hn = z * h0v + (1.f - z) * ht;
            int n = nb + m;
            if (wmask) {
                if (wmask[n]) hout[(size_t)n * HH + c] = hn;
            } else {
                hout[(size_t)n * HH + c] = hn;
            }
            if (DOHEAD) s_z[m][c] = hn;
        }
    }

    if (DOHEAD) {
        __syncthreads();
        for (int i = tid; i < 16 * FF; i += 256) {
            int m = i / FF, f = i - m * FF;
            float acc = headb[f];
#pragma unroll 8
            for (int cJ = 0; cJ < HH; cJ++) acc += s_z[m][cJ] * headW[cJ * FF + f];
            y[(size_t)nb * FF + i] = acc;
        }
    }
}

extern "C" void kernel_launch(void* const* d_in, const int* in_sizes, int n_in,
                              void* d_out, int out_size, void* d_ws, size_t ws_size,
                              hipStream_t stream) {
    const float* x_seq = (const float*)d_in[0];
    const int*   ei    = (const int*)d_in[1];
    const float* ea    = (const float*)d_in[2];
    const unsigned char* mraw = (const unsigned char*)d_in[3];
    const float* Wz  = (const float*)d_in[5];
    const float* Wr  = (const float*)d_in[6];
    const float* Wh  = (const float*)d_in[7];
    const float* bz  = (const float*)d_in[8];
    const float* br  = (const float*)d_in[9];
    const float* bh  = (const float*)d_in[10];
    const float* LWz = (const float*)d_in[11];
    const float* LWr = (const float*)d_in[12];
    const float* LWh = (const float*)d_in[13];
    const float* Lbz = (const float*)d_in[14];
    const float* Lbr = (const float*)d_in[15];
    const float* Lbh = (const float*)d_in[16];
    const float* headW = (const float*)d_in[17];
    const float* headb = (const float*)d_in[18];
    float* out = (float*)d_out;

    char* wp = (char*)d_ws;
    int*   cnt    = (int*)wp;   wp += sizeof(int) * TT * NN;          // histogram
    int*   cursor = (int*)wp;   wp += sizeof(int) * TT * NN;
    int*   offs   = (int*)wp;   wp += sizeof(int) * TT * (NN + 1);
    int*   srcs   = (int*)wp;   wp += sizeof(int) * (size_t)TT * EE;
    float* eav    = (float*)wp; wp += sizeof(float) * (size_t)TT * EE;
    float* dinv   = (float*)wp; wp += sizeof(float) * TT * NN;
    float* hstore = (float*)wp; wp += sizeof(float) * (size_t)NN * HH;
    float* hp     = (float*)wp; wp += sizeof(float) * (size_t)NN * HH;
    float* xebuf  = (float*)wp; wp += sizeof(float) * NN * FF;
    float* Call   = (float*)wp; wp += sizeof(float) * 3 * FF * HH;
    float* b2     = (float*)wp; wp += sizeof(float) * 3 * HH;
    int*   mflag  = (int*)wp;   wp += 256;
    unsigned char* mask = (unsigned char*)wp; wp += TT * NN;
    if (ws_size < (size_t)(wp - (char*)d_ws)) return;

    hipMemsetAsync(mflag, 0, sizeof(int), stream);
    k_maskdetect<<<64, 256, 0, stream>>>(mraw, mflag);
    k_maskconv<<<(TT * NN + 255) / 256, 256, 0, stream>>>(mraw, mflag, mask);

    // CSR build + norm coefficients (once for all 12 graphs)
    hipMemsetAsync(cnt, 0, sizeof(int) * TT * NN, stream);
    hipMemsetAsync(hstore, 0, sizeof(float) * NN * HH, stream);
    k_hist<<<(TT * EE + 255) / 256, 256, 0, stream>>>(ei, cnt);
    k_scan<<<TT, 1024, 0, stream>>>(cnt, offs, cursor);
    k_fill<<<(TT * EE + 255) / 256, 256, 0, stream>>>(ei, ea, cursor, srcs, eav);
    k_degdinv<<<(TT * NN + 255) / 256, 256, 0, stream>>>(offs, eav, dinv);
    k_coef<<<(TT * NN + 255) / 256, 256, 0, stream>>>(offs, srcs, dinv, eav);
    k_fold<<<3, 128, 0, stream>>>(Wz, Wr, Wh, bz, br, bh, LWz, LWr, LWh, Lbz, Lbr, Lbh, Call, b2);

    // ---------------- encoder ----------------
    for (int t = 0; t < TT; t++) {
        const float* xt = x_seq + (size_t)t * NN * FF;
        const unsigned char* mt = mask + (size_t)t * NN;
        k_gather<<<(NN * FF + 255) / 256, 256, 0, stream>>>(
            xt, offs + t * (NN + 1), srcs + (size_t)t * EE, eav + (size_t)t * EE,
            dinv + t * NN, xebuf);
        k_cell<0><<<NN / 16, 256, 0, stream>>>(
            xebuf, hstore, mt, Call, b2, LWz, LWr, LWh, mt, hstore,
            nullptr, nullptr, nullptr);
    }

    // ---------------- decoder ----------------
    const int*   offsl = offs + (TT - 1) * (NN + 1);
    const int*   srcsl = srcs + (size_t)(TT - 1) * EE;
    const float* eavl  = eav + (size_t)(TT - 1) * EE;
    const float* dil   = dinv + (TT - 1) * NN;
    for (int k = 0; k < HORZ; k++) {
        const float* xin = (k == 0) ? (x_seq + (size_t)(TT - 1) * NN * FF)
                                    : (out + (size_t)(k - 1) * NN * FF);
        k_gather<<<(NN * FF + 255) / 256, 256, 0, stream>>>(
            xin, offsl, srcsl, eavl, dil, xebuf);
        k_cell<1><<<NN / 16, 256, 0, stream>>>(
            xebuf, (k == 0) ? hstore : hp,
            (k == 0) ? (mask + (size_t)(TT - 1) * NN) : nullptr,
            Call, b2, LWz, LWr, LWh, nullptr, hp,
            headW, headb, out + (size_t)k * NN * FF);
    }
}